// Round 5
// baseline (237.158 us; speedup 1.0000x reference)
//
#include <hip/hip_runtime.h>
#include <math.h>

// Problem constants (fixed by setup_inputs)
#define BB   8
#define CH   64     // C_in = C_out
#define NN   4096
#define KK   16
#define TILE 64     // nodes per tile
#define NT   1024   // 16 waves
#define NBLK 256    // grid: must stay <= 256 so 1 block/CU guarantees residency
#define PP   72     // LDS pitch (bf16) for 64-wide rows  (144 B, 16B-aligned)
#define CP   136    // LDS pitch (bf16) for 128-wide rows (272 B, 16B-aligned)
#define CNT_OFF (8u << 20)   // barrier counter lives at d_ws + 8 MB (preB = 4 MB)

typedef __attribute__((ext_vector_type(8))) short bf16x8;   // 8 bf16 = 4 VGPR
typedef __attribute__((ext_vector_type(4))) float f32x4;
typedef __attribute__((ext_vector_type(4))) unsigned short u16x4;

__device__ inline unsigned f2bf(float f) {   // RNE f32 -> bf16 bits
    union { float f; unsigned u; } v; v.f = f;
    return (v.u + 0x7FFFu + ((v.u >> 16) & 1u)) >> 16;
}

// packed per-16-bit unsigned max on 4 bf16 lanes (relu>=0 -> bits order)
__device__ inline uint2 pkmax(uint2 a, uint2 b) {
#if __has_builtin(__builtin_elementwise_max)
    u16x4 r = __builtin_elementwise_max(*(u16x4*)&a, *(u16x4*)&b);
    return *(uint2*)&r;
#else
    uint2 r;
    r.x = (((a.x >> 16) > (b.x >> 16)) ? (a.x & 0xFFFF0000u) : (b.x & 0xFFFF0000u))
        | (((a.x & 0xFFFFu) > (b.x & 0xFFFFu)) ? (a.x & 0xFFFFu) : (b.x & 0xFFFFu));
    r.y = (((a.y >> 16) > (b.y >> 16)) ? (a.y & 0xFFFF0000u) : (b.y & 0xFFFF0000u))
        | (((a.y & 0xFFFFu) > (b.y & 0xFFFFu)) ? (a.y & 0xFFFFu) : (b.y & 0xFFFFu));
    return r;
#endif
}

__global__ void zero_cnt(unsigned* c) { *c = 0u; }

// ---------------------------------------------------------------------------
// Fused kernel, plain launch + software global barrier.
//  Phase A (x2 tiles): preB[b][n][o] = bf16(relu(w_pre @ x[b][:,n])) node-major
//  barrier (threadfence + agent-scope counter, all 256 blocks co-resident)
//  Phase B (x2 tiles): aggr = max_k preB[idx_k] (packed bf16 bit-max);
//      cat=[x,aggr]; out = relu(w_nn @ cat)+bias; L2-normalize; store.
// Block map: b = idx&7 (XCD swizzle), tile pair p = idx>>3 (0..31).
// Wave map (MFMA): mt=wv&3 (16 out ch), nt=wv>>2 (16 nodes).
// ---------------------------------------------------------------------------
__global__ __launch_bounds__(NT, 4) void fused_kernel(
    const float* __restrict__ x,       // [B][CH][NN] f32
    const float* __restrict__ w_pre,   // [CH][CH] f32
    const float* __restrict__ w_nn,    // [CH][2*CH] f32
    const float* __restrict__ bias,    // [CH] f32
    const int*   __restrict__ edge0,   // [B][NN][KK] int32
    unsigned short* __restrict__ preB, // [B][NN][CH] bf16 (workspace)
    unsigned* __restrict__ cnt,        // barrier counter (pre-zeroed)
    float* __restrict__ out)           // [B][CH][NN] f32
{
    __shared__ unsigned short catT[TILE * CP]; // [node][c]: c<64 x, c>=64 aggr
    __shared__ unsigned short wP[CH * PP];     // w_pre bf16 [o][c]
    __shared__ unsigned short wN[CH * CP];     // w_nn  bf16 [o][c]
    __shared__ float part[TILE][4];
    const int t    = threadIdx.x;
    const int lane = t & 63;
    const int wv   = __builtin_amdgcn_readfirstlane(t >> 6);  // 0..15 uniform
    const int b    = blockIdx.x & 7;
    const int p    = blockIdx.x >> 3;          // tile pair 0..31
    const int mt = wv & 3, nt = wv >> 2, nl = lane & 15, q = lane >> 4;

    // ---- Early latency-hidden loads: idx for both tiles, bias ----
    const int idx0 = edge0[((size_t)b * NN + (p * 2 + 0) * TILE + wv * 4) * KK + lane];
    const int idx1 = edge0[((size_t)b * NN + (p * 2 + 1) * TILE + wv * 4) * KK + lane];
    float bia[4];
#pragma unroll
    for (int r = 0; r < 4; ++r) bia[r] = bias[mt * 16 + q * 4 + r];

    // ---- Stage weights once ----
    {   // w_nn: thread t -> row o=t>>4, cols (t&15)*8..+7
        const int o = t >> 4, c0 = (t & 15) * 8;
        const float4 wa = *(const float4*)&w_nn[o * 2 * CH + c0];
        const float4 wb = *(const float4*)&w_nn[o * 2 * CH + c0 + 4];
        uint4 pk;
        pk.x = f2bf(wa.x) | (f2bf(wa.y) << 16);
        pk.y = f2bf(wa.z) | (f2bf(wa.w) << 16);
        pk.z = f2bf(wb.x) | (f2bf(wb.y) << 16);
        pk.w = f2bf(wb.z) | (f2bf(wb.w) << 16);
        *(uint4*)&wN[o * CP + c0] = pk;
    }
    {   // w_pre: thread t -> row o=t>>4, cols (t&15)*4..+3
        const int o = t >> 4, c0 = (t & 15) * 4;
        const float4 w = *(const float4*)&w_pre[o * CH + c0];
        uint2 pk; pk.x = f2bf(w.x) | (f2bf(w.y) << 16);
        pk.y = f2bf(w.z) | (f2bf(w.w) << 16);
        *(uint2*)&wP[o * PP + c0] = pk;
    }

    // ---- Phase A: pre = relu(w_pre @ x_tile) for tiles 2p, 2p+1 ----
#pragma unroll
    for (int s = 0; s < 2; ++s) {
        const int n0 = (p * 2 + s) * TILE;
        __syncthreads();     // catT reuse guard (also covers weight staging)
        {   // stage x tile as bf16, node-major
            const int c0 = wv * 4;
            unsigned h[4];
#pragma unroll
            for (int pp = 0; pp < 4; ++pp)
                h[pp] = f2bf(x[((size_t)b * CH + c0 + pp) * NN + n0 + lane]);
            uint2 pk; pk.x = h[0] | (h[1] << 16); pk.y = h[2] | (h[3] << 16);
            *(uint2*)&catT[lane * CP + c0] = pk;
        }
        __syncthreads();
        const bf16x8 a0 = *(const bf16x8*)&wP[(mt * 16 + nl) * PP + q * 8];
        const bf16x8 a1 = *(const bf16x8*)&wP[(mt * 16 + nl) * PP + 32 + q * 8];
        const bf16x8 b0 = *(const bf16x8*)&catT[(nt * 16 + nl) * CP + q * 8];
        const bf16x8 b1 = *(const bf16x8*)&catT[(nt * 16 + nl) * CP + 32 + q * 8];
        f32x4 acc = {0.f, 0.f, 0.f, 0.f};
        acc = __builtin_amdgcn_mfma_f32_16x16x32_bf16(a0, b0, acc, 0, 0, 0);
        acc = __builtin_amdgcn_mfma_f32_16x16x32_bf16(a1, b1, acc, 0, 0, 0);
        // D: col=nl (node), row=q*4+r (out ch); 4 consecutive o -> 8B store
        const int n = n0 + nt * 16 + nl;
        const unsigned h0 = f2bf(fmaxf(acc[0], 0.f)), h1 = f2bf(fmaxf(acc[1], 0.f));
        const unsigned h2 = f2bf(fmaxf(acc[2], 0.f)), h3 = f2bf(fmaxf(acc[3], 0.f));
        uint2 pk; pk.x = h0 | (h1 << 16); pk.y = h2 | (h3 << 16);
        *(uint2*)&preB[((size_t)b * NN + n) * CH + mt * 16 + q * 4] = pk;
    }

    // ---- Software global barrier (all NBLK blocks are co-resident) ----
    __threadfence();                 // release this thread's preB stores
    __syncthreads();                 // whole block's stores fenced
    if (t == 0) {
        __hip_atomic_fetch_add(cnt, 1u, __ATOMIC_RELEASE, __HIP_MEMORY_SCOPE_AGENT);
        while (__hip_atomic_load(cnt, __ATOMIC_ACQUIRE, __HIP_MEMORY_SCOPE_AGENT) < NBLK)
            __builtin_amdgcn_s_sleep(8);
    }
    __syncthreads();
    __threadfence();                 // acquire: invalidate L1 before gather

    // ---- Phase B: gather-max + main MFMA + normalize, tiles 2p, 2p+1 ----
#pragma unroll
    for (int s = 0; s < 2; ++s) {
        const int n0 = (p * 2 + s) * TILE;
        const int idxv = s ? idx1 : idx0;
        {   // stage x tile into catT[:,0:64]
            const int c0 = wv * 4;
            unsigned h[4];
#pragma unroll
            for (int pp = 0; pp < 4; ++pp)
                h[pp] = f2bf(x[((size_t)b * CH + c0 + pp) * NN + n0 + lane]);
            uint2 pk; pk.x = h[0] | (h[1] << 16); pk.y = h[2] | (h[3] << 16);
            *(uint2*)&catT[lane * CP + c0] = pk;
        }
        {   // gather-max: 4 nodes/instr. lane: i=lane>>4 node, c0=(lane&15)*4 ch
            const int i = lane >> 4, c0 = (lane & 15) * 4;
            const unsigned short* pb = preB + (size_t)b * NN * CH + c0;
            uint2 ag; ag.x = 0u; ag.y = 0u;
#pragma unroll
            for (int k = 0; k < KK; ++k) {
                const int nb = __shfl(idxv, (lane & 48) | k, 64) & (NN - 1);
                const uint2 v = *(const uint2*)&pb[(size_t)nb * CH];
                ag = pkmax(ag, v);
            }
            *(uint2*)&catT[(wv * 4 + i) * CP + CH + c0] = ag;
        }
        __syncthreads();

        // main MFMA: K=128 over cat=[x, aggr]
        f32x4 acc = {0.f, 0.f, 0.f, 0.f};
#pragma unroll
        for (int kq = 0; kq < 4; ++kq) {
            const bf16x8 af = *(const bf16x8*)&wN[(mt * 16 + nl) * CP + kq * 32 + q * 8];
            const bf16x8 bf = *(const bf16x8*)&catT[(nt * 16 + nl) * CP + kq * 32 + q * 8];
            acc = __builtin_amdgcn_mfma_f32_16x16x32_bf16(af, bf, acc, 0, 0, 0);
        }

        // epilogue: relu+bias, sum-of-squares over 64 ch, normalize, store
        float v[4], ss = 0.f;
#pragma unroll
        for (int r = 0; r < 4; ++r) {
            v[r] = fmaxf(acc[r], 0.f) + bia[r];
            ss += v[r] * v[r];
        }
        ss += __shfl_xor(ss, 16, 64);
        ss += __shfl_xor(ss, 32, 64);
        if (lane < 16) part[nt * 16 + nl][mt] = ss;
        __syncthreads();
        const float s4 = part[nt * 16 + nl][0] + part[nt * 16 + nl][1]
                       + part[nt * 16 + nl][2] + part[nt * 16 + nl][3];
        const float scale = 1.f / fmaxf(sqrtf(s4), 1e-12f);
        const int n = n0 + nt * 16 + nl;
#pragma unroll
        for (int r = 0; r < 4; ++r)
            out[((size_t)b * CH + mt * 16 + q * 4 + r) * NN + n] = v[r] * scale;
        __syncthreads();   // catT/part reuse guard for next tile
    }
}

extern "C" void kernel_launch(void* const* d_in, const int* in_sizes, int n_in,
                              void* d_out, int out_size, void* d_ws, size_t ws_size,
                              hipStream_t stream) {
    const float* x     = (const float*)d_in[0];
    // d_in[1] = x_0 : unused by the reference
    const float* w_pre = (const float*)d_in[2];
    const float* w_nn  = (const float*)d_in[3];
    const float* bias  = (const float*)d_in[4];
    const int*   edge  = (const int*)d_in[5];   // [2][B][NN][KK]; slice 0

    unsigned short* preB = (unsigned short*)d_ws;          // 4 MB
    unsigned* cnt = (unsigned*)((char*)d_ws + CNT_OFF);    // barrier counter
    float* outp = (float*)d_out;

    zero_cnt<<<1, 1, 0, stream>>>(cnt);
    fused_kernel<<<dim3(NBLK), dim3(NT), 0, stream>>>(
        x, w_pre, w_nn, bias, edge, preB, cnt, outp);
}

// Round 6
// 86.211 us; speedup vs baseline: 2.7509x; 2.7509x over previous
//
#include <hip/hip_runtime.h>
#include <math.h>

// Problem constants (fixed by setup_inputs)
#define BB   8
#define CH   64     // C_in = C_out
#define NN   4096
#define KK   16
#define TILE 64     // nodes per block
#define NT   1024   // 16 waves
#define PP   72     // LDS pitch (bf16) for 64-wide rows  (144 B, 16B-aligned)
#define CP   136    // LDS pitch (bf16) for 128-wide rows (272 B, 16B-aligned)

typedef __attribute__((ext_vector_type(8))) short bf16x8;   // 8 bf16 = 4 VGPR
typedef __attribute__((ext_vector_type(4))) float f32x4;
typedef __attribute__((ext_vector_type(4))) unsigned short u16x4;

__device__ inline unsigned f2bf(float f) {   // RNE f32 -> bf16 bits
    union { float f; unsigned u; } v; v.f = f;
    return (v.u + 0x7FFFu + ((v.u >> 16) & 1u)) >> 16;
}

// packed per-16-bit unsigned max on 4 bf16 values (relu>=0 -> bits order)
__device__ inline uint2 pkmax(uint2 a, uint2 b) {
#if __has_builtin(__builtin_elementwise_max)
    u16x4 r = __builtin_elementwise_max(*(u16x4*)&a, *(u16x4*)&b);
    return *(uint2*)&r;
#else
    uint2 r;
    r.x = (((a.x >> 16) > (b.x >> 16)) ? (a.x & 0xFFFF0000u) : (b.x & 0xFFFF0000u))
        | (((a.x & 0xFFFFu) > (b.x & 0xFFFFu)) ? (a.x & 0xFFFFu) : (b.x & 0xFFFFu));
    r.y = (((a.y >> 16) > (b.y >> 16)) ? (a.y & 0xFFFF0000u) : (b.y & 0xFFFF0000u))
        | (((a.y & 0xFFFFu) > (b.y & 0xFFFFu)) ? (a.y & 0xFFFFu) : (b.y & 0xFFFFu));
    return r;
#endif
}

// Swizzle: b = idx&7 keeps each batch's blocks on one XCD; pre_kernel writes
// preB[b] and main_kernel reads preB[b] from the SAME XCD's L2 (512KB/batch).
__device__ inline void decode_block(int bi, int& b, int& n0) {
    b = bi & 7; n0 = (bi >> 3) * TILE;
}

// ---------------------------------------------------------------------------
// Kernel A: preB[b][n][o] = bf16( relu( w_pre @ x[b][:,n] ) ), node-major.
// MFMA 16x16x32 bf16: wave wv -> mt=wv&3 (16 out ch), nt=wv>>2 (16 nodes).
// ---------------------------------------------------------------------------
__global__ __launch_bounds__(NT, 8) void pre_kernel(
    const float* __restrict__ x,      // [B][CH][NN] f32
    const float* __restrict__ w_pre,  // [CH][CH] f32
    unsigned short* __restrict__ preB)// [B][NN][CH] bf16
{
    __shared__ unsigned short xT[TILE * PP];  // [node][c]
    __shared__ unsigned short wS[CH * PP];    // [o][c]
    const int t    = threadIdx.x;
    const int lane = t & 63;
    const int wv   = __builtin_amdgcn_readfirstlane(t >> 6);
    int b, n0; decode_block(blockIdx.x, b, n0);

    // Stage x tile as bf16: 4 consecutive channels/thread -> one ds_write_b64
    {
        const int c0 = wv * 4;
        unsigned h[4];
#pragma unroll
        for (int p = 0; p < 4; ++p)
            h[p] = f2bf(x[((size_t)b * CH + c0 + p) * NN + n0 + lane]);
        uint2 pk; pk.x = h[0] | (h[1] << 16); pk.y = h[2] | (h[3] << 16);
        *(uint2*)&xT[lane * PP + c0] = pk;
    }
    // Stage w_pre as bf16: thread t -> row o=t>>4, cols (t&15)*4..+3
    {
        const int o = t >> 4, c0 = (t & 15) * 4;
        const float4 w = *(const float4*)&w_pre[o * CH + c0];
        uint2 pk; pk.x = f2bf(w.x) | (f2bf(w.y) << 16);
        pk.y = f2bf(w.z) | (f2bf(w.w) << 16);
        *(uint2*)&wS[o * PP + c0] = pk;
    }
    __syncthreads();

    const int mt = wv & 3, nt = wv >> 2, nl = lane & 15, q = lane >> 4;
    const bf16x8 a0 = *(const bf16x8*)&wS[(mt * 16 + nl) * PP + q * 8];
    const bf16x8 a1 = *(const bf16x8*)&wS[(mt * 16 + nl) * PP + 32 + q * 8];
    const bf16x8 b0 = *(const bf16x8*)&xT[(nt * 16 + nl) * PP + q * 8];
    const bf16x8 b1 = *(const bf16x8*)&xT[(nt * 16 + nl) * PP + 32 + q * 8];
    f32x4 acc = {0.f, 0.f, 0.f, 0.f};
    acc = __builtin_amdgcn_mfma_f32_16x16x32_bf16(a0, b0, acc, 0, 0, 0);
    acc = __builtin_amdgcn_mfma_f32_16x16x32_bf16(a1, b1, acc, 0, 0, 0);

    // D: col=nl (node), row=q*4+r (out ch). 4 consecutive o -> 8B store.
    const int n = n0 + nt * 16 + nl;
    const unsigned h0 = f2bf(fmaxf(acc[0], 0.f)), h1 = f2bf(fmaxf(acc[1], 0.f));
    const unsigned h2 = f2bf(fmaxf(acc[2], 0.f)), h3 = f2bf(fmaxf(acc[3], 0.f));
    uint2 pk; pk.x = h0 | (h1 << 16); pk.y = h2 | (h3 << 16);
    *(uint2*)&preB[((size_t)b * NN + n) * CH + mt * 16 + q * 4] = pk;
}

// ---------------------------------------------------------------------------
// Kernel B: aggr = max_k preB[idx_k] (packed bf16 bit-max, 4 nodes/instr);
//           cat=[x, aggr] bf16; out = relu(w_nn @ cat)+bias; L2-normalize.
// ---------------------------------------------------------------------------
__global__ __launch_bounds__(NT, 8) void main_kernel(
    const float* __restrict__ x,            // [B][CH][NN] f32
    const unsigned short* __restrict__ preB,// [B][NN][CH] bf16
    const float* __restrict__ w_nn,         // [CH][2*CH] f32
    const float* __restrict__ bias,         // [CH] f32
    const int* __restrict__ edge0,          // [B][NN][KK] int32
    float* __restrict__ out)                // [B][CH][NN] f32
{
    __shared__ unsigned short catT[TILE * CP];  // [node][c]: c<64 x, c>=64 aggr
    __shared__ unsigned short wS[CH * CP];      // [o][c]
    __shared__ float part[TILE][4];
    const int t    = threadIdx.x;
    const int lane = t & 63;
    const int wv   = __builtin_amdgcn_readfirstlane(t >> 6);
    int b, n0; decode_block(blockIdx.x, b, n0);

    // idx early (latency): one coalesced load covers this wave's 4 nodes
    const int idxv = edge0[((size_t)b * NN + n0 + wv * 4) * KK + lane];

    // Stage w_nn as bf16: thread t -> row o=t>>4, cols (t&15)*8..+7 (b128)
    {
        const int o = t >> 4, c0 = (t & 15) * 8;
        const float4 wa = *(const float4*)&w_nn[o * 2 * CH + c0];
        const float4 wb = *(const float4*)&w_nn[o * 2 * CH + c0 + 4];
        uint4 pk;
        pk.x = f2bf(wa.x) | (f2bf(wa.y) << 16);
        pk.y = f2bf(wa.z) | (f2bf(wa.w) << 16);
        pk.z = f2bf(wb.x) | (f2bf(wb.y) << 16);
        pk.w = f2bf(wb.z) | (f2bf(wb.w) << 16);
        *(uint4*)&wS[o * CP + c0] = pk;
    }
    // Stage x tile as bf16 into catT[node][0..63]
    {
        const int c0 = wv * 4;
        unsigned h[4];
#pragma unroll
        for (int p = 0; p < 4; ++p)
            h[p] = f2bf(x[((size_t)b * CH + c0 + p) * NN + n0 + lane]);
        uint2 pk; pk.x = h[0] | (h[1] << 16); pk.y = h[2] | (h[3] << 16);
        *(uint2*)&catT[lane * CP + c0] = pk;
    }
    // Gather-max, packed: wave wv owns nodes wv*4..+3.
    // lane: i=lane>>4 selects node, c0=(lane&15)*4 selects 4 channels (8B).
    // relu output >= 0 -> bf16 bits are monotone -> packed unsigned max.
    {
        const int i = lane >> 4, c0 = (lane & 15) * 4;
        const unsigned short* pb = preB + (size_t)b * NN * CH + c0;
        uint2 ag; ag.x = 0u; ag.y = 0u;
#pragma unroll
        for (int k = 0; k < KK; ++k) {
            const int nb = __shfl(idxv, (lane & 48) | k, 64) & (NN - 1);
            const uint2 v = *(const uint2*)&pb[(size_t)nb * CH];
            ag = pkmax(ag, v);
        }
        *(uint2*)&catT[(wv * 4 + i) * CP + CH + c0] = ag;
    }
    __syncthreads();

    // MFMA: wave wv -> mt (16 out ch) x nt (16 nodes); K=128 over cat.
    const int mt = wv & 3, nt = wv >> 2, nl = lane & 15, q = lane >> 4;
    f32x4 acc = {0.f, 0.f, 0.f, 0.f};
#pragma unroll
    for (int kq = 0; kq < 4; ++kq) {
        const bf16x8 af = *(const bf16x8*)&wS[(mt * 16 + nl) * CP + kq * 32 + q * 8];
        const bf16x8 bf = *(const bf16x8*)&catT[(nt * 16 + nl) * CP + kq * 32 + q * 8];
        acc = __builtin_amdgcn_mfma_f32_16x16x32_bf16(af, bf, acc, 0, 0, 0);
    }

    // Epilogue: relu+bias, sum-of-squares over 64 ch (quads + m-tiles), norm.
    float v[4], ss = 0.f;
#pragma unroll
    for (int r = 0; r < 4; ++r) {
        v[r] = fmaxf(acc[r], 0.f) + bias[mt * 16 + q * 4 + r];
        ss += v[r] * v[r];
    }
    ss += __shfl_xor(ss, 16, 64);   // reduce across quads (rows within m-tile)
    ss += __shfl_xor(ss, 32, 64);
    if (lane < 16) part[nt * 16 + nl][mt] = ss;
    __syncthreads();
    const float s4 = part[nt * 16 + nl][0] + part[nt * 16 + nl][1]
                   + part[nt * 16 + nl][2] + part[nt * 16 + nl][3];
    const float scale = 1.f / fmaxf(sqrtf(s4), 1e-12f);

    // Store: per reg r, lanes of a quad cover 16 consecutive n (64B segments)
    const int n = n0 + nt * 16 + nl;
#pragma unroll
    for (int r = 0; r < 4; ++r)
        out[((size_t)b * CH + mt * 16 + q * 4 + r) * NN + n] = v[r] * scale;
}

extern "C" void kernel_launch(void* const* d_in, const int* in_sizes, int n_in,
                              void* d_out, int out_size, void* d_ws, size_t ws_size,
                              hipStream_t stream) {
    const float* x     = (const float*)d_in[0];
    // d_in[1] = x_0 : unused by the reference
    const float* w_pre = (const float*)d_in[2];
    const float* w_nn  = (const float*)d_in[3];
    const float* bias  = (const float*)d_in[4];
    const int*   edge  = (const int*)d_in[5];   // [2][B][NN][KK]; slice 0

    unsigned short* preB = (unsigned short*)d_ws;  // B*NN*CH bf16 = 4 MB
    float* outp = (float*)d_out;

    const dim3 grid(BB * NN / TILE);   // 512 blocks
    const dim3 block(NT);
    pre_kernel<<<grid, block, 0, stream>>>(x, w_pre, preB);
    main_kernel<<<grid, block, 0, stream>>>(x, preB, w_nn, bias, edge, outp);
}